// Round 11
// baseline (3813.935 us; speedup 1.0000x reference)
//
#include <hip/hip_runtime.h>
#include <stdint.h>

#pragma clang fp contract(off)

#define N_ANCH 262144
#define BATCH 8
#define TOPK 5000
#define PROP 1000
#define SORTN 8192
#define NEGF -1000000000.0f
#define MAXR 4.135166556742356f
#define NMS_T 1024

__device__ __forceinline__ unsigned ord32(float f){
  unsigned u = __float_as_uint(f);
  return (u & 0x80000000u) ? ~u : (u | 0x80000000u);
}
__device__ __forceinline__ float unord32(unsigned o){
  unsigned u = (o & 0x80000000u) ? (o & 0x7FFFFFFFu) : ~o;
  return __uint_as_float(u);
}

// masked score for (b, i)
__device__ __forceinline__ float masked_score(const float* __restrict__ score,
                                              const float4* __restrict__ anchors,
                                              int b, int i){
  float4 a = anchors[i];
  bool valid = (a.z <= 1.0f) && (a.w <= 1.0f) && (a.x >= 0.0f) && (a.y >= 0.0f);
  float s = score[(size_t)b*N_ANCH + i];
  return valid ? s : -1.0f;
}

// Pass 1: histogram of top-16 bits of ordered score (only s >= 0.5)
__global__ void k_hist1(const float* __restrict__ score, const float4* __restrict__ anchors,
                        unsigned* __restrict__ hist){
  int b = blockIdx.y;
  int i = blockIdx.x*blockDim.x + threadIdx.x;
  float s = masked_score(score, anchors, b, i);
  unsigned o = ord32(s);
  if (o >= 0xBF000000u)  // s >= 0.5
    atomicAdd(&hist[(size_t)b*65536u + (o>>16)], 1u);
}

__global__ void k_find1(const unsigned* __restrict__ hist, unsigned* __restrict__ meta){
  int b = blockIdx.x; int t = threadIdx.x;
  __shared__ unsigned part[256];
  const unsigned* h = hist + (size_t)b*65536u;
  unsigned sum = 0;
  for (int k=0;k<256;++k) sum += h[t*256+k];
  part[t]=sum; __syncthreads();
  if (t==0){
    unsigned cum=0; int tr=0;
    for (int q=255;q>=0;--q){ if (cum + part[q] >= TOPK){ tr=q; break;} cum += part[q]; }
    unsigned b1 = tr*256; unsigned cA = cum;
    for (int bin=tr*256+255; bin>=tr*256; --bin){
      unsigned hh = h[bin];
      if (cA + hh >= TOPK){ b1 = (unsigned)bin; break; }
      cA += hh;
    }
    meta[b*8+0]=b1; meta[b*8+1]=cA;
  }
}

__global__ void k_hist2(const float* __restrict__ score, const float4* __restrict__ anchors,
                        const unsigned* __restrict__ meta, unsigned* __restrict__ hist){
  int b = blockIdx.y;
  int i = blockIdx.x*blockDim.x + threadIdx.x;
  float s = masked_score(score, anchors, b, i);
  unsigned o = ord32(s);
  unsigned b1 = meta[b*8+0];
  if ((o>>16) == b1)
    atomicAdd(&hist[(size_t)b*65536u + (o & 0xFFFFu)], 1u);
}

__global__ void k_find2(const unsigned* __restrict__ hist, unsigned* __restrict__ meta){
  int b = blockIdx.x; int t = threadIdx.x;
  __shared__ unsigned part[256];
  const unsigned* h = hist + (size_t)b*65536u;
  unsigned sum=0;
  for (int k=0;k<256;++k) sum += h[t*256+k];
  part[t]=sum; __syncthreads();
  if (t==0){
    unsigned cum = meta[b*8+1];
    int tr=0;
    for (int q=255;q>=0;--q){ if (cum+part[q] >= TOPK){tr=q;break;} cum+=part[q]; }
    unsigned b2 = tr*256;
    for (int bin=tr*256+255; bin>=tr*256; --bin){
      unsigned hh=h[bin];
      if (cum+hh >= TOPK){ b2=(unsigned)bin; break; }
      cum+=hh;
    }
    meta[b*8+2] = (meta[b*8+0]<<16) | b2;  // exact 32-bit ordered-score threshold
  }
}

__global__ void k_compact(const float* __restrict__ score, const float4* __restrict__ anchors,
                          unsigned* __restrict__ meta,
                          unsigned long long* __restrict__ cand, unsigned* __restrict__ candEq){
  int b = blockIdx.y;
  int i = blockIdx.x*blockDim.x + threadIdx.x;
  float s = masked_score(score, anchors, b, i);
  unsigned o = ord32(s);
  unsigned T = meta[b*8+2];
  if (o > T){
    unsigned pos = atomicAdd(&meta[b*8+3], 1u);
    if (pos < SORTN) cand[(size_t)b*SORTN + pos] = (((unsigned long long)(~o)) << 32) | (unsigned)i;
  } else if (o == T){
    unsigned pos = atomicAdd(&meta[b*8+4], 1u);
    if (pos < SORTN) candEq[(size_t)b*SORTN + pos] = (unsigned)i;
  }
}

// Bitonic-sort candidates (pad to 8192), emit first 5000 keys (stable top-k order)
__global__ void __launch_bounds__(1024) k_sort(const unsigned* __restrict__ meta,
                       const unsigned long long* __restrict__ cand,
                       const unsigned* __restrict__ candEq,
                       unsigned long long* __restrict__ sorted){
  __shared__ unsigned long long keys[SORTN];
  int b = blockIdx.x; int t = threadIdx.x;
  unsigned cntA = meta[b*8+3];
  unsigned cntEq = meta[b*8+4];
  if (cntA > (unsigned)SORTN) cntA = SORTN;
  if (cntEq > (unsigned)SORTN - cntA) cntEq = SORTN - cntA;
  unsigned tot = cntA + cntEq;
  unsigned T = meta[b*8+2];
  unsigned long long eqHi = ((unsigned long long)(~T)) << 32;
  for (unsigned j=t; j<SORTN; j+=1024u){
    unsigned long long k;
    if (j < cntA) k = cand[(size_t)b*SORTN + j];
    else if (j < tot) k = eqHi | candEq[(size_t)b*SORTN + (j - cntA)];
    else k = ~0ull;
    keys[j]=k;
  }
  __syncthreads();
  for (unsigned k=2;k<=SORTN;k<<=1){
    for (unsigned j=k>>1;j>0;j>>=1){
      for (unsigned i=t;i<SORTN;i+=1024u){
        unsigned l = i ^ j;
        if (l > i){
          unsigned long long a = keys[i], c = keys[l];
          bool up = ((i & k) == 0u);
          if ((a > c) == up){ keys[i]=c; keys[l]=a; }
        }
      }
      __syncthreads();
    }
  }
  for (unsigned j=t;j<TOPK;j+=1024u) sorted[(size_t)b*TOPK + j] = keys[j];
}

// Per-element score update + argmax step. Box read from LDS (read-only data),
// area recomputed (bit-identical to storing it). ~12 locals — small macro.
#define NMS_UPD(J, S_) do{                                                   \
  int j_ = (J);                                                              \
  if (it > 0){                                                               \
    if (j_ == prevBest){                                                     \
      S_ = NEGF;                                                             \
    } else {                                                                 \
      float4 B_ = bx4[j_];                                                   \
      float ltx_ = fmaxf(bbx, B_.x);                                         \
      float lty_ = fmaxf(bby, B_.y);                                         \
      float rbx_ = fminf(bbz, B_.z);                                         \
      float rby_ = fminf(bbw, B_.w);                                         \
      float iw_ = fmaxf(rbx_-ltx_, 0.f);                                     \
      float ih_ = fmaxf(rby_-lty_, 0.f);                                     \
      float inter_ = iw_*ih_;                                                \
      float aj_ = (B_.z-B_.x)*(B_.w-B_.y);                                   \
      float iou_ = inter_/(ba + aj_ - inter_ + 1e-12f);                      \
      S_ = S_*expf(-(iou_*iou_));                                            \
    }                                                                        \
  }                                                                          \
  if (S_ > bs){ bs = S_; bp = j_; }                                          \
}while(0)

// Sequential soft-NMS: 1024 threads/block (16 waves = 4/SIMD), one block/batch.
// Boxes in LDS (read-only, re-read per iter); ONLY scores live in registers
// (5 named scalars) -> zero private arrays, zero scratch by construction.
__global__ void __launch_bounds__(NMS_T) k_nms(const unsigned long long* __restrict__ sorted,
                      const float4* __restrict__ anchors, const float4* __restrict__ regress,
                      float* __restrict__ out){
  __shared__ float4 bx4[TOPK];     // 80 KB
  __shared__ float  scin[TOPK];    // 20 KB (init staging only)
  __shared__ unsigned long long pk[16];
  int b = blockIdx.x; int t = threadIdx.x;
  // gather + delta2bbox + clip (round-1 structure: plain strided loop)
  for (int j=t; j<TOPK; j+=NMS_T){
    unsigned long long key = sorted[(size_t)b*TOPK + j];
    unsigned o = ~(unsigned)(key>>32);
    unsigned idx = (unsigned)key;
    float s = unord32(o);
    float4 a = anchors[idx];
    float4 d = regress[(size_t)b*N_ANCH + idx];
    float dx = d.x*0.1f, dy = d.y*0.1f;
    float dw = d.z*0.2f, dh = d.w*0.2f;
    dw = fminf(fmaxf(dw, -MAXR), MAXR);
    dh = fminf(fmaxf(dh, -MAXR), MAXR);
    float aw = a.z - a.x, ah = a.w - a.y;
    float cx = (a.z + a.x)*0.5f, cy = (a.w + a.y)*0.5f;
    float ncx = cx + dx*aw, ncy = cy + dy*ah;
    float nw = aw*expf(dw), nh = ah*expf(dh);
    float x1 = ncx - nw*0.5f, y1 = ncy - nh*0.5f;
    float x2 = ncx + nw*0.5f, y2 = ncy + nh*0.5f;
    x1 = fminf(fmaxf(x1,0.f),1.f); y1 = fminf(fmaxf(y1,0.f),1.f);
    x2 = fminf(fmaxf(x2,0.f),1.f); y2 = fminf(fmaxf(y2,0.f),1.f);
    bx4[j] = make_float4(x1,y1,x2,y2);
    scin[j] = s;
  }
  __syncthreads();
  float S0 = scin[t];
  float S1 = scin[t + 1*NMS_T];
  float S2 = scin[t + 2*NMS_T];
  float S3 = scin[t + 3*NMS_T];
  float S4 = (t + 4*NMS_T < TOPK) ? scin[t + 4*NMS_T] : -INFINITY;
  int lane = t & 63, wid = t >> 6;
  int prevBest = -1;
  float bbx=0.f, bby=0.f, bbz=0.f, bbw=0.f;
  float ba = 0.f;
  for (int it=0; it<PROP; ++it){
    float bs = -INFINITY; int bp = 0;
    NMS_UPD(t + 0*NMS_T, S0);
    NMS_UPD(t + 1*NMS_T, S1);
    NMS_UPD(t + 2*NMS_T, S2);
    NMS_UPD(t + 3*NMS_T, S3);
    if (t + 4*NMS_T < TOPK) NMS_UPD(t + 4*NMS_T, S4);
    // key: score desc, then slot asc (== stable first-occurrence argmax)
    unsigned long long key = (((unsigned long long)ord32(bs))<<32) | (unsigned)(0xFFFFFFFFu - (unsigned)bp);
    #pragma unroll
    for (int m=1;m<64;m<<=1){
      unsigned long long k2 = __shfl_xor(key, m);
      if (k2 > key) key = k2;
    }
    if (lane==0) pk[wid] = key;
    __syncthreads();
    #pragma unroll
    for (int w=0;w<16;++w){
      unsigned long long k2 = pk[w];
      if (k2 > key) key = k2;
    }
    int p = (int)(0xFFFFFFFFu - (unsigned)key);
    prevBest = p;
    float4 bbv = bx4[p];
    bbx = bbv.x; bby = bbv.y; bbz = bbv.z; bbw = bbv.w;
    ba = (bbz-bbx)*(bbw-bby);
    if (t==0){
      float s = unord32((unsigned)(key>>32));
      float4 ob = (s > NEGF*0.5f) ? bbv : make_float4(0.f,0.f,0.f,0.f);
      *(float4*)(out + ((size_t)b*PROP + it)*4) = ob;
    }
    __syncthreads();  // pk reads done before next iteration's write
  }
}

extern "C" void kernel_launch(void* const* d_in, const int* in_sizes, int n_in,
                              void* d_out, int out_size, void* d_ws, size_t ws_size,
                              hipStream_t stream){
  const float*  score   = (const float*) d_in[0];
  const float4* regress = (const float4*)d_in[1];
  const float4* anchors = (const float4*)d_in[2];
  float* out = (float*)d_out;
  char* ws = (char*)d_ws;
  // ws layout — total use: 2 MB + 1 KB. cand/candEq/sorted ALIAS the hist
  // region (hist is dead after k_find2; stream order serializes the reuse).
  unsigned* hist = (unsigned*)(ws + 0);                          // [0, 2MB)
  unsigned* meta = (unsigned*)(ws + 2097152);                    // [2MB, 2MB+256B)
  unsigned long long* cand   = (unsigned long long*)(ws + 0);    // [0, 512KB)       alias
  unsigned* candEq           = (unsigned*)(ws + 524288);         // [512KB, 768KB)   alias
  unsigned long long* sorted = (unsigned long long*)(ws + 786432); // [768KB, ~1.08MB) alias

  hipMemsetAsync(ws, 0, 2097152 + 1024, stream);  // hist + meta
  dim3 g1(N_ANCH/256, BATCH);
  k_hist1<<<g1, 256, 0, stream>>>(score, anchors, hist);
  k_find1<<<BATCH, 256, 0, stream>>>(hist, meta);
  hipMemsetAsync(hist, 0, 2097152, stream);
  k_hist2<<<g1, 256, 0, stream>>>(score, anchors, meta, hist);
  k_find2<<<BATCH, 256, 0, stream>>>(hist, meta);
  k_compact<<<g1, 256, 0, stream>>>(score, anchors, meta, cand, candEq);
  k_sort<<<BATCH, 1024, 0, stream>>>(meta, cand, candEq, sorted);
  k_nms<<<BATCH, NMS_T, 0, stream>>>(sorted, anchors, regress, out);
}

// Round 12
// 3171.913 us; speedup vs baseline: 1.2024x; 1.2024x over previous
//
#include <hip/hip_runtime.h>
#include <stdint.h>

#pragma clang fp contract(off)

#define N_ANCH 262144
#define BATCH 8
#define TOPK 5000
#define PROP 1000
#define SORTN 8192
#define NEGF -1000000000.0f
#define MAXR 4.135166556742356f
#define NMS_T 512
#define HBINS 256

__device__ __forceinline__ unsigned ord32(float f){
  unsigned u = __float_as_uint(f);
  return (u & 0x80000000u) ? ~u : (u | 0x80000000u);
}
__device__ __forceinline__ float unord32(unsigned o){
  unsigned u = (o & 0x80000000u) ? (o & 0x7FFFFFFFu) : ~o;
  return __uint_as_float(u);
}

// masked score for (b, i)
__device__ __forceinline__ float masked_score(const float* __restrict__ score,
                                              const float4* __restrict__ anchors,
                                              int b, int i){
  float4 a = anchors[i];
  bool valid = (a.z <= 1.0f) && (a.w <= 1.0f) && (a.x >= 0.0f) && (a.y >= 0.0f);
  float s = score[(size_t)b*N_ANCH + i];
  return valid ? s : -1.0f;
}

// Scores >= 0.5 have ordered bits in [0xBF000000, 0xBF800000] -> only 129
// distinct top-16-bit buckets. LDS-staged 129-bin histogram, one pass.
__global__ void k_hist1(const float* __restrict__ score, const float4* __restrict__ anchors,
                        unsigned* __restrict__ hist){
  __shared__ unsigned lh[HBINS];
  int b = blockIdx.y; int t = threadIdx.x;
  lh[t] = 0; __syncthreads();
  int base = blockIdx.x * 8192;
  for (int r = 0; r < 32; ++r){
    int i = base + r*256 + t;
    float s = masked_score(score, anchors, b, i);
    unsigned o = ord32(s);
    if (o >= 0xBF000000u){
      int bin = (int)(o >> 16) - 0xBF00;   // 0..128
      atomicAdd(&lh[bin], 1u);
    }
  }
  __syncthreads();
  unsigned v = lh[t];
  if (v) atomicAdd(&hist[(size_t)b*HBINS + t], v);
}

// Find the 16-bit bucket containing rank-5000 (from top); threshold = bucket floor.
// Compacting o >= T yields (strict-above < 5000) + (bucket pop ~720) <= ~5750 < 8192.
__global__ void k_find1(const unsigned* __restrict__ hist, unsigned* __restrict__ meta){
  int b = blockIdx.x; int t = threadIdx.x;
  __shared__ unsigned part[HBINS];
  part[t] = hist[(size_t)b*HBINS + t];
  __syncthreads();
  if (t == 0){
    unsigned cum = 0; int bsel = 0;
    for (int bin = 128; bin >= 0; --bin){
      cum += part[bin];
      if (cum >= TOPK){ bsel = bin; break; }
    }
    meta[b*8+2] = ((unsigned)(0xBF00 + bsel)) << 16;  // bucket-floor threshold
  }
}

// Compact all candidates with o >= T into cand (key = ~o<<32 | idx:
// sorts score desc, then anchor idx asc — exact stable top_k order).
__global__ void k_compact(const float* __restrict__ score, const float4* __restrict__ anchors,
                          unsigned* __restrict__ meta, unsigned long long* __restrict__ cand){
  int b = blockIdx.y;
  int i = blockIdx.x*blockDim.x + threadIdx.x;
  float s = masked_score(score, anchors, b, i);
  unsigned o = ord32(s);
  unsigned T = meta[b*8+2];
  if (o >= T){
    unsigned pos = atomicAdd(&meta[b*8+3], 1u);
    if (pos < SORTN) cand[(size_t)b*SORTN + pos] = (((unsigned long long)(~o)) << 32) | (unsigned)i;
  }
}

// Bitonic-sort candidates (pad to 8192), emit first 5000 keys (stable top-k order)
__global__ void __launch_bounds__(1024) k_sort(const unsigned* __restrict__ meta,
                       const unsigned long long* __restrict__ cand,
                       unsigned long long* __restrict__ sorted){
  __shared__ unsigned long long keys[SORTN];
  int b = blockIdx.x; int t = threadIdx.x;
  unsigned cnt = meta[b*8+3];
  if (cnt > (unsigned)SORTN) cnt = SORTN;
  for (unsigned j = t; j < SORTN; j += 1024u)
    keys[j] = (j < cnt) ? cand[(size_t)b*SORTN + j] : ~0ull;
  __syncthreads();
  for (unsigned k = 2; k <= SORTN; k <<= 1){
    for (unsigned j = k>>1; j > 0; j >>= 1){
      for (unsigned i = t; i < SORTN; i += 1024u){
        unsigned l = i ^ j;
        if (l > i){
          unsigned long long a = keys[i], c = keys[l];
          bool up = ((i & k) == 0u);
          if ((a > c) == up){ keys[i] = c; keys[l] = a; }
        }
      }
      __syncthreads();
    }
  }
  for (unsigned j = t; j < TOPK; j += 1024u) sorted[(size_t)b*TOPK + j] = keys[j];
}

// Per-element score update + argmax step. Box read from LDS (read-only data),
// area recomputed (bit-identical to storing it).
#define NMS_UPD(J, S_) do{                                                   \
  int j_ = (J);                                                              \
  if (it > 0){                                                               \
    if (j_ == prevBest){                                                     \
      S_ = NEGF;                                                             \
    } else {                                                                 \
      float4 B_ = bx4[j_];                                                   \
      float ltx_ = fmaxf(bbx, B_.x);                                         \
      float lty_ = fmaxf(bby, B_.y);                                         \
      float rbx_ = fminf(bbz, B_.z);                                         \
      float rby_ = fminf(bbw, B_.w);                                         \
      float iw_ = fmaxf(rbx_-ltx_, 0.f);                                     \
      float ih_ = fmaxf(rby_-lty_, 0.f);                                     \
      float inter_ = iw_*ih_;                                                \
      float aj_ = (B_.z-B_.x)*(B_.w-B_.y);                                   \
      float iou_ = inter_/(ba + aj_ - inter_ + 1e-12f);                      \
      S_ = S_*expf(-(iou_*iou_));                                            \
    }                                                                        \
  }                                                                          \
  if (S_ > bs){ bs = S_; bp = j_; }                                          \
}while(0)

// Sequential soft-NMS: 512 threads (8 waves = 2/SIMD), one block/batch.
// Boxes in LDS (read-only, re-read per iter); scores in 10 named registers.
// 8-wave geometry: half the barrier + pk-scan overhead of the 16-wave version.
__global__ void __launch_bounds__(NMS_T) k_nms(const unsigned long long* __restrict__ sorted,
                      const float4* __restrict__ anchors, const float4* __restrict__ regress,
                      float* __restrict__ out){
  __shared__ float4 bx4[TOPK];     // 80 KB
  __shared__ float  scin[TOPK];    // 20 KB (init staging only)
  __shared__ unsigned long long pk[8];
  int b = blockIdx.x; int t = threadIdx.x;
  // gather + delta2bbox + clip (plain strided loop)
  for (int j = t; j < TOPK; j += NMS_T){
    unsigned long long key = sorted[(size_t)b*TOPK + j];
    unsigned o = ~(unsigned)(key>>32);
    unsigned idx = (unsigned)key;
    float s = unord32(o);
    float4 a = anchors[idx];
    float4 d = regress[(size_t)b*N_ANCH + idx];
    float dx = d.x*0.1f, dy = d.y*0.1f;
    float dw = d.z*0.2f, dh = d.w*0.2f;
    dw = fminf(fmaxf(dw, -MAXR), MAXR);
    dh = fminf(fmaxf(dh, -MAXR), MAXR);
    float aw = a.z - a.x, ah = a.w - a.y;
    float cx = (a.z + a.x)*0.5f, cy = (a.w + a.y)*0.5f;
    float ncx = cx + dx*aw, ncy = cy + dy*ah;
    float nw = aw*expf(dw), nh = ah*expf(dh);
    float x1 = ncx - nw*0.5f, y1 = ncy - nh*0.5f;
    float x2 = ncx + nw*0.5f, y2 = ncy + nh*0.5f;
    x1 = fminf(fmaxf(x1,0.f),1.f); y1 = fminf(fmaxf(y1,0.f),1.f);
    x2 = fminf(fmaxf(x2,0.f),1.f); y2 = fminf(fmaxf(y2,0.f),1.f);
    bx4[j] = make_float4(x1,y1,x2,y2);
    scin[j] = s;
  }
  __syncthreads();
  float S0 = scin[t + 0*NMS_T];
  float S1 = scin[t + 1*NMS_T];
  float S2 = scin[t + 2*NMS_T];
  float S3 = scin[t + 3*NMS_T];
  float S4 = scin[t + 4*NMS_T];
  float S5 = scin[t + 5*NMS_T];
  float S6 = scin[t + 6*NMS_T];
  float S7 = scin[t + 7*NMS_T];
  float S8 = scin[t + 8*NMS_T];
  float S9 = (t + 9*NMS_T < TOPK) ? scin[t + 9*NMS_T] : -INFINITY;
  int lane = t & 63, wid = t >> 6;
  int prevBest = -1;
  float bbx = 0.f, bby = 0.f, bbz = 0.f, bbw = 0.f;
  float ba = 0.f;
  for (int it = 0; it < PROP; ++it){
    float bs = -INFINITY; int bp = 0;
    NMS_UPD(t + 0*NMS_T, S0);
    NMS_UPD(t + 1*NMS_T, S1);
    NMS_UPD(t + 2*NMS_T, S2);
    NMS_UPD(t + 3*NMS_T, S3);
    NMS_UPD(t + 4*NMS_T, S4);
    NMS_UPD(t + 5*NMS_T, S5);
    NMS_UPD(t + 6*NMS_T, S6);
    NMS_UPD(t + 7*NMS_T, S7);
    NMS_UPD(t + 8*NMS_T, S8);
    if (t + 9*NMS_T < TOPK) NMS_UPD(t + 9*NMS_T, S9);
    // key: score desc, then slot asc (== stable first-occurrence argmax)
    unsigned long long key = (((unsigned long long)ord32(bs))<<32) | (unsigned)(0xFFFFFFFFu - (unsigned)bp);
    #pragma unroll
    for (int m = 1; m < 64; m <<= 1){
      unsigned long long k2 = __shfl_xor(key, m);
      if (k2 > key) key = k2;
    }
    if (lane == 0) pk[wid] = key;
    __syncthreads();
    #pragma unroll
    for (int w = 0; w < 8; ++w){
      unsigned long long k2 = pk[w];
      if (k2 > key) key = k2;
    }
    int p = (int)(0xFFFFFFFFu - (unsigned)key);
    prevBest = p;
    float4 bbv = bx4[p];
    bbx = bbv.x; bby = bbv.y; bbz = bbv.z; bbw = bbv.w;
    ba = (bbz-bbx)*(bbw-bby);
    if (t == 0){
      float s = unord32((unsigned)(key>>32));
      float4 ob = (s > NEGF*0.5f) ? bbv : make_float4(0.f,0.f,0.f,0.f);
      *(float4*)(out + ((size_t)b*PROP + it)*4) = ob;
    }
    __syncthreads();  // pk reads done before next iteration's write
  }
}

extern "C" void kernel_launch(void* const* d_in, const int* in_sizes, int n_in,
                              void* d_out, int out_size, void* d_ws, size_t ws_size,
                              hipStream_t stream){
  const float*  score   = (const float*) d_in[0];
  const float4* regress = (const float4*)d_in[1];
  const float4* anchors = (const float4*)d_in[2];
  float* out = (float*)d_out;
  char* ws = (char*)d_ws;
  // ws layout — total ~1.1 MB (well under the proven-safe 2 MB+1 KB footprint):
  unsigned* hist = (unsigned*)(ws + 0);                            // [0, 8KB)  8 batches x 256 bins
  unsigned* meta = (unsigned*)(ws + 8192);                         // [8KB, 8KB+256B)
  unsigned long long* cand   = (unsigned long long*)(ws + 16384);  // [16KB, 16KB+512KB)
  unsigned long long* sorted = (unsigned long long*)(ws + 16384 + 524288); // 8*5000*8 = 320KB

  hipMemsetAsync(ws, 0, 16384, stream);  // hist + meta (incl. atomic counters)
  dim3 gh(N_ANCH/8192, BATCH);
  k_hist1<<<gh, 256, 0, stream>>>(score, anchors, hist);
  k_find1<<<BATCH, HBINS, 0, stream>>>(hist, meta);
  dim3 gc(N_ANCH/256, BATCH);
  k_compact<<<gc, 256, 0, stream>>>(score, anchors, meta, cand);
  k_sort<<<BATCH, 1024, 0, stream>>>(meta, cand, sorted);
  k_nms<<<BATCH, NMS_T, 0, stream>>>(sorted, anchors, regress, out);
}

// Round 13
// 2701.906 us; speedup vs baseline: 1.4116x; 1.1740x over previous
//
#include <hip/hip_runtime.h>
#include <stdint.h>

#pragma clang fp contract(off)

#define N_ANCH 262144
#define BATCH 8
#define TOPK 5000
#define PROP 1000
#define SORTN 8192
#define NEGF -1000000000.0f
#define MAXR 4.135166556742356f
#define NMS_T 512
#define NMS_K 10
#define HBINS 256

__device__ __forceinline__ unsigned ord32(float f){
  unsigned u = __float_as_uint(f);
  return (u & 0x80000000u) ? ~u : (u | 0x80000000u);
}
__device__ __forceinline__ float unord32(unsigned o){
  unsigned u = (o & 0x80000000u) ? (o & 0x7FFFFFFFu) : ~o;
  return __uint_as_float(u);
}

// masked score for (b, i)
__device__ __forceinline__ float masked_score(const float* __restrict__ score,
                                              const float4* __restrict__ anchors,
                                              int b, int i){
  float4 a = anchors[i];
  bool valid = (a.z <= 1.0f) && (a.w <= 1.0f) && (a.x >= 0.0f) && (a.y >= 0.0f);
  float s = score[(size_t)b*N_ANCH + i];
  return valid ? s : -1.0f;
}

// Scores >= 0.5 have ordered bits in [0xBF000000, 0xBF800000] -> only 129
// distinct top-16-bit buckets. LDS-staged 129-bin histogram, one pass.
__global__ void k_hist1(const float* __restrict__ score, const float4* __restrict__ anchors,
                        unsigned* __restrict__ hist){
  __shared__ unsigned lh[HBINS];
  int b = blockIdx.y; int t = threadIdx.x;
  lh[t] = 0; __syncthreads();
  int base = blockIdx.x * 8192;
  for (int r = 0; r < 32; ++r){
    int i = base + r*256 + t;
    float s = masked_score(score, anchors, b, i);
    unsigned o = ord32(s);
    if (o >= 0xBF000000u){
      int bin = (int)(o >> 16) - 0xBF00;   // 0..128
      atomicAdd(&lh[bin], 1u);
    }
  }
  __syncthreads();
  unsigned v = lh[t];
  if (v) atomicAdd(&hist[(size_t)b*HBINS + t], v);
}

// Find the 16-bit bucket containing rank-5000 (from top); threshold = bucket floor.
__global__ void k_find1(const unsigned* __restrict__ hist, unsigned* __restrict__ meta){
  int b = blockIdx.x; int t = threadIdx.x;
  __shared__ unsigned part[HBINS];
  part[t] = hist[(size_t)b*HBINS + t];
  __syncthreads();
  if (t == 0){
    unsigned cum = 0; int bsel = 0;
    for (int bin = 128; bin >= 0; --bin){
      cum += part[bin];
      if (cum >= TOPK){ bsel = bin; break; }
    }
    meta[b*8+2] = ((unsigned)(0xBF00 + bsel)) << 16;  // bucket-floor threshold
  }
}

// Compact all candidates with o >= T (key = ~o<<32 | idx: score desc, idx asc).
__global__ void k_compact(const float* __restrict__ score, const float4* __restrict__ anchors,
                          unsigned* __restrict__ meta, unsigned long long* __restrict__ cand){
  int b = blockIdx.y;
  int i = blockIdx.x*blockDim.x + threadIdx.x;
  float s = masked_score(score, anchors, b, i);
  unsigned o = ord32(s);
  unsigned T = meta[b*8+2];
  if (o >= T){
    unsigned pos = atomicAdd(&meta[b*8+3], 1u);
    if (pos < SORTN) cand[(size_t)b*SORTN + pos] = (((unsigned long long)(~o)) << 32) | (unsigned)i;
  }
}

// Bitonic-sort candidates (pad to 8192), emit first 5000 keys (stable top-k order)
__global__ void __launch_bounds__(1024) k_sort(const unsigned* __restrict__ meta,
                       const unsigned long long* __restrict__ cand,
                       unsigned long long* __restrict__ sorted){
  __shared__ unsigned long long keys[SORTN];
  int b = blockIdx.x; int t = threadIdx.x;
  unsigned cnt = meta[b*8+3];
  if (cnt > (unsigned)SORTN) cnt = SORTN;
  for (unsigned j = t; j < SORTN; j += 1024u)
    keys[j] = (j < cnt) ? cand[(size_t)b*SORTN + j] : ~0ull;
  __syncthreads();
  for (unsigned k = 2; k <= SORTN; k <<= 1){
    for (unsigned j = k>>1; j > 0; j >>= 1){
      for (unsigned i = t; i < SORTN; i += 1024u){
        unsigned l = i ^ j;
        if (l > i){
          unsigned long long a = keys[i], c = keys[l];
          bool up = ((i & k) == 0u);
          if ((a > c) == up){ keys[i] = c; keys[l] = a; }
        }
      }
      __syncthreads();
    }
  }
  for (unsigned j = t; j < TOPK; j += 1024u) sorted[(size_t)b*TOPK + j] = keys[j];
}

// Sequential soft-NMS: 512 threads/block, one block per batch.
// EXACT round-6 structure (measured best: per-thread arrays, fused update+argmax,
// bx4 LDS broadcast) with ONE delta: double-buffered pk -> 1 barrier/iter.
__global__ void __launch_bounds__(NMS_T) k_nms(const unsigned long long* __restrict__ sorted,
                      const float4* __restrict__ anchors, const float4* __restrict__ regress,
                      float* __restrict__ out){
  __shared__ float4 bx4[TOPK];
  __shared__ unsigned long long pk[2][8];
  int b = blockIdx.x; int t = threadIdx.x;
  float4 bbx[NMS_K]; float sar[NMS_K]; float sco[NMS_K];
  #pragma unroll
  for (int k=0;k<NMS_K;++k){
    int j = t + k*NMS_T;
    if (j < TOPK){
      unsigned long long key = sorted[(size_t)b*TOPK + j];
      unsigned o = ~(unsigned)(key>>32);
      unsigned idx = (unsigned)key;
      float s = unord32(o);
      float4 a = anchors[idx];
      float4 d = regress[(size_t)b*N_ANCH + idx];
      float dx = d.x*0.1f, dy = d.y*0.1f;
      float dw = d.z*0.2f, dh = d.w*0.2f;
      dw = fminf(fmaxf(dw, -MAXR), MAXR);
      dh = fminf(fmaxf(dh, -MAXR), MAXR);
      float aw = a.z - a.x, ah = a.w - a.y;
      float cx = (a.z + a.x)*0.5f, cy = (a.w + a.y)*0.5f;
      float ncx = cx + dx*aw, ncy = cy + dy*ah;
      float nw = aw*expf(dw), nh = ah*expf(dh);
      float x1 = ncx - nw*0.5f, y1 = ncy - nh*0.5f;
      float x2 = ncx + nw*0.5f, y2 = ncy + nh*0.5f;
      x1 = fminf(fmaxf(x1,0.f),1.f); y1 = fminf(fmaxf(y1,0.f),1.f);
      x2 = fminf(fmaxf(x2,0.f),1.f); y2 = fminf(fmaxf(y2,0.f),1.f);
      float4 box = make_float4(x1,y1,x2,y2);
      bbx[k] = box; bx4[j] = box;
      sar[k] = (x2-x1)*(y2-y1);
      sco[k] = s;
    } else {
      bbx[k] = make_float4(0.f,0.f,0.f,0.f);
      sar[k] = 0.f;
      sco[k] = -INFINITY;
    }
  }
  __syncthreads();
  int lane = t & 63, wid = t >> 6;
  int prevBest = -1;
  float4 bb = make_float4(0.f,0.f,0.f,0.f);
  float ba = 0.f;
  for (int it=0; it<PROP; ++it){
    float bs = -INFINITY; int bp = 0;
    #pragma unroll
    for (int k=0;k<NMS_K;++k){
      int j = t + k*NMS_T;
      bool inb = (k < NMS_K-1) || (j < TOPK);
      if (inb){
        if (it > 0){
          if (j == prevBest){
            sco[k] = NEGF;
          } else {
            float ltx = fmaxf(bb.x, bbx[k].x);
            float lty = fmaxf(bb.y, bbx[k].y);
            float rbx = fminf(bb.z, bbx[k].z);
            float rby = fminf(bb.w, bbx[k].w);
            float iw = fmaxf(rbx-ltx, 0.f);
            float ih = fmaxf(rby-lty, 0.f);
            float inter = iw*ih;
            float iou = inter/(ba + sar[k] - inter + 1e-12f);
            sco[k] = sco[k]*expf(-(iou*iou));
          }
        }
        if (sco[k] > bs){ bs = sco[k]; bp = j; }
      }
    }
    // key: score desc, then slot asc (== stable first-occurrence argmax)
    unsigned long long key = (((unsigned long long)ord32(bs))<<32) | (unsigned)(0xFFFFFFFFu - (unsigned)bp);
    #pragma unroll
    for (int m=1;m<64;m<<=1){
      unsigned long long k2 = __shfl_xor(key, m);
      if (k2 > key) key = k2;
    }
    int buf = it & 1;
    if (lane==0) pk[buf][wid] = key;
    __syncthreads();
    #pragma unroll
    for (int w=0;w<8;++w){
      unsigned long long k2 = pk[buf][w];
      if (k2 > key) key = k2;
    }
    int p = (int)(0xFFFFFFFFu - (unsigned)key);
    prevBest = p;
    bb = bx4[p];
    ba = (bb.z-bb.x)*(bb.w-bb.y);
    if (t==0){
      float s = unord32((unsigned)(key>>32));
      float4 ob = (s > NEGF*0.5f) ? bb : make_float4(0.f,0.f,0.f,0.f);
      *(float4*)(out + ((size_t)b*PROP + it)*4) = ob;
    }
  }
}

extern "C" void kernel_launch(void* const* d_in, const int* in_sizes, int n_in,
                              void* d_out, int out_size, void* d_ws, size_t ws_size,
                              hipStream_t stream){
  const float*  score   = (const float*) d_in[0];
  const float4* regress = (const float4*)d_in[1];
  const float4* anchors = (const float4*)d_in[2];
  float* out = (float*)d_out;
  char* ws = (char*)d_ws;
  // ws layout — total ~850 KB:
  unsigned* hist = (unsigned*)(ws + 0);                            // [0, 8KB)
  unsigned* meta = (unsigned*)(ws + 8192);                         // [8KB, +256B)
  unsigned long long* cand   = (unsigned long long*)(ws + 16384);  // 512 KB
  unsigned long long* sorted = (unsigned long long*)(ws + 16384 + 524288); // 320 KB

  hipMemsetAsync(ws, 0, 16384, stream);  // hist + meta (incl. atomic counters)
  dim3 gh(N_ANCH/8192, BATCH);
  k_hist1<<<gh, 256, 0, stream>>>(score, anchors, hist);
  k_find1<<<BATCH, HBINS, 0, stream>>>(hist, meta);
  dim3 gc(N_ANCH/256, BATCH);
  k_compact<<<gc, 256, 0, stream>>>(score, anchors, meta, cand);
  k_sort<<<BATCH, 1024, 0, stream>>>(meta, cand, sorted);
  k_nms<<<BATCH, NMS_T, 0, stream>>>(sorted, anchors, regress, out);
}